// Round 17
// baseline (1108.628 us; speedup 1.0000x reference)
//
#include <hip/hip_runtime.h>
#include <math.h>

#define NN 3136      // H*W = 56*56
#define CC 96
#define BB 8
#define KNB 9
#define PARTS 7      // 7 parts x 14 m-tiles x 32 = 3136 cols
#define FLT_MAX_ 3.402823466e+38f
typedef unsigned long long u64;
typedef unsigned short ushortT;
typedef __attribute__((ext_vector_type(8))) short short8;   // 8 bf16 (4 VGPR)
typedef __attribute__((ext_vector_type(4))) float f32x4;

// ---------------------------------------------------------------------------
// 1x1 conv as batched GEMM (baseline version, known-good)
// ---------------------------------------------------------------------------
__global__ __launch_bounds__(256) void conv1_kernel(
    const float* __restrict__ in, const float* __restrict__ w,
    const float* __restrict__ bias, float* __restrict__ out, int K, int O)
{
    __shared__ float sW[16][64];   // [kk][o]
    __shared__ float sX[16][64];   // [kk][n]
    const int b  = blockIdx.z;
    const int n0 = blockIdx.x * 64;
    const int o0 = blockIdx.y * 64;
    const int tid = threadIdx.x;
    const int tx = tid & 15, ty = tid >> 4;
    const float* inb = in + (size_t)b * K * NN;

    float acc[4][4] = {{0.f}};

    for (int kb = 0; kb < K; kb += 16) {
        __syncthreads();
        {
            int o  = tid >> 2;
            int k4 = (tid & 3) << 2;
            float4 wv = make_float4(0.f, 0.f, 0.f, 0.f);
            if (o0 + o < O)
                wv = *(const float4*)&w[(size_t)(o0 + o) * K + kb + k4];
            sW[k4 + 0][o] = wv.x; sW[k4 + 1][o] = wv.y;
            sW[k4 + 2][o] = wv.z; sW[k4 + 3][o] = wv.w;
        }
        #pragma unroll
        for (int i = 0; i < 4; i++) {
            int e = tid + i * 256;
            int kk = e >> 6, n2 = e & 63;
            sX[kk][n2] = inb[(size_t)(kb + kk) * NN + n0 + n2];
        }
        __syncthreads();
        #pragma unroll
        for (int kk = 0; kk < 16; kk++) {
            const float4 av = *(const float4*)&sW[kk][ty << 2];
            const float4 xv = *(const float4*)&sX[kk][tx << 2];
            float a_[4] = {av.x, av.y, av.z, av.w};
            float x_[4] = {xv.x, xv.y, xv.z, xv.w};
            #pragma unroll
            for (int i = 0; i < 4; i++)
                #pragma unroll
                for (int j = 0; j < 4; j++)
                    acc[i][j] = fmaf(a_[i], x_[j], acc[i][j]);
        }
    }
    #pragma unroll
    for (int i = 0; i < 4; i++) {
        int o = o0 + (ty << 2) + i;
        if (o < O) {
            float bo = bias[o];
            float4 v = make_float4(acc[i][0] + bo, acc[i][1] + bo,
                                   acc[i][2] + bo, acc[i][3] + bo);
            *(float4*)&out[((size_t)b * O + o) * NN + n0 + (tx << 2)] = v;
        }
    }
}

// ---------------------------------------------------------------------------
// Instance norm over N per (b,c) row; act: 0 none, 1 gelu, 2 relu
// ---------------------------------------------------------------------------
__global__ __launch_bounds__(256) void inorm_kernel(
    const float* __restrict__ in, float* __restrict__ out,
    const float* __restrict__ res, int act)
{
    const int row = blockIdx.x;
    const float* x = in + (size_t)row * NN;
    const int tid = threadIdx.x;

    float v[13];
    float s = 0.f;
    #pragma unroll
    for (int i = 0; i < 13; i++) {
        int idx = tid + i * 256;
        v[i] = (idx < NN) ? x[idx] : 0.f;
        s += v[i];
    }
    __shared__ float red[4];
    #pragma unroll
    for (int off = 32; off > 0; off >>= 1) s += __shfl_down(s, off);
    if ((tid & 63) == 0) red[tid >> 6] = s;
    __syncthreads();
    const float mean = (red[0] + red[1] + red[2] + red[3]) * (1.f / (float)NN);

    float s2 = 0.f;
    #pragma unroll
    for (int i = 0; i < 13; i++) {
        int idx = tid + i * 256;
        if (idx < NN) { float d = v[i] - mean; s2 = fmaf(d, d, s2); }
    }
    #pragma unroll
    for (int off = 32; off > 0; off >>= 1) s2 += __shfl_down(s2, off);
    __syncthreads();
    if ((tid & 63) == 0) red[tid >> 6] = s2;
    __syncthreads();
    const float var = (red[0] + red[1] + red[2] + red[3]) * (1.f / (float)NN);
    const float rs = rsqrtf(var + 1e-5f);

    float* o = out + (size_t)row * NN;
    const float* rr = res ? (res + (size_t)row * NN) : nullptr;
    #pragma unroll
    for (int i = 0; i < 13; i++) {
        int idx = tid + i * 256;
        if (idx < NN) {
            float y = (v[i] - mean) * rs;
            if (act == 1)      y = 0.5f * y * (1.f + erff(y * 0.70710678118654752f));
            else if (act == 2) y = fmaxf(y, 0.f);
            if (rr) y += rr[idx];
            o[idx] = y;
        }
    }
}

// ---------------------------------------------------------------------------
// bf16 round-to-nearest-even helper
// ---------------------------------------------------------------------------
__device__ __forceinline__ unsigned bf16rne(float x)
{
    unsigned u = __float_as_uint(x);
    return (u + 0x7fffu + ((u >> 16) & 1u)) >> 16;
}

// ---------------------------------------------------------------------------
// Column (channel) L2-normalize; emit 3-way bf16 split (h+m+l == xn to
// ~2^-25) in [b][n][c] layout + sq[b,n] = sum_c xn^2 (fp32).
// ---------------------------------------------------------------------------
__global__ __launch_bounds__(256) void colnorm_kernel(
    const float* __restrict__ xf, ushortT* __restrict__ xh,
    ushortT* __restrict__ xm, ushortT* __restrict__ xl,
    float* __restrict__ sqc)
{
    const int g = blockIdx.x * 256 + threadIdx.x;   // over B*N
    const int b = g / NN;
    const int n = g - b * NN;
    const float* p = xf + (size_t)b * CC * NN + n;

    float s = 0.f;
    for (int c = 0; c < CC; c++) { float t = p[(size_t)c * NN]; s = fmaf(t, t, s); }
    const float den = fmaxf(sqrtf(s), 1e-12f);

    const size_t o = (size_t)g * CC;
    float sq = 0.f;
    for (int c = 0; c < CC; c++) {
        float t = p[(size_t)c * NN] / den;
        sq = fmaf(t, t, sq);
        unsigned hr = bf16rne(t);
        float hf = __uint_as_float(hr << 16);
        float r1 = t - hf;
        unsigned mr = bf16rne(r1);
        float mf = __uint_as_float(mr << 16);
        float r2 = r1 - mf;
        unsigned lr = bf16rne(r2);
        xh[o + c] = (ushortT)hr;
        xm[o + c] = (ushortT)mr;
        xl[o + c] = (ushortT)lr;
    }
    sqc[g] = sq;
}

// ---------------------------------------------------------------------------
// u64-key top-9: key = (ord(dist) << 32) | m.  min-u64 == (min d, then min m)
// ---------------------------------------------------------------------------
__device__ __forceinline__ u64 dkey(float d, int m)
{
    unsigned int ub = __float_as_uint(d);
    ub ^= (unsigned int)(((int)ub) >> 31) | 0x80000000u;
    return ((u64)ub << 32) | (unsigned int)m;
}
__device__ __forceinline__ void ins9u(u64 (&kk)[9], u64 key)
{
    if (key < kk[8]) {
        kk[8] = key;
        #pragma unroll
        for (int j = 8; j > 0; --j) {
            if (kk[j] < kk[j - 1]) {
                u64 t = kk[j]; kk[j] = kk[j - 1]; kk[j - 1] = t;
            }
        }
    }
}

// ---------------------------------------------------------------------------
// Fused distance GEMM (MFMA, bf16 3-split) + top-9 select (v8).
// Operand-SWAPPED mfma: pass the m-side fragment as operand A and the
// r-side fragment as operand B -> output D^T. Under the m89 C/D map
// (col=lane&15, row=(lane>>4)*4+q) each lane then holds ONE row r=fr and
// FOUR m-candidates acc[q] -- selection runs directly on the accumulator
// registers with a single kk list/thread. shD roundtrip and its barrier
// are eliminated; shB is double-buffered with ONE barrier per m-tile
// (conv1-style ping-pong). k-permutation cancellation & dot symmetry
// arguments unchanged (both fragments built identically; v6/v7 passed).
// grid: (NN/64, PARTS, BB), 512 threads = 8 waves (4 Rt x 2 Mt).
// ---------------------------------------------------------------------------
__global__ __launch_bounds__(512, 4) void knn_mfma_kernel(
    const ushortT* __restrict__ xh, const ushortT* __restrict__ xm,
    const ushortT* __restrict__ xl, const float* __restrict__ sqc,
    const float* __restrict__ rp, u64* __restrict__ pko)
{
    __shared__ ushortT shB[2][3][32][104];  // [buf][split][m][c] 2x19.5KB
    const int b    = blockIdx.z;
    const int part = blockIdx.y;
    const int r0   = blockIdx.x * 64;
    const int tid  = threadIdx.x;
    const int w  = tid >> 6;             // wave 0..7
    const int l  = tid & 63;             // lane
    const int Rt = w & 3;                // row-tile
    const int Mt = w >> 2;               // col-half of the 32-col m-tile
    const int fr = l & 15;               // fragment index
    const int fq = l >> 4;               // k-quad
    const float* sqb = sqc + (size_t)b * NN;

    // A-side (r) fragments: once per block from global (operand-B role now)
    const int r = r0 + Rt * 16 + fr;
    const size_t arow = ((size_t)(b * NN + r)) * CC;
    const int ko = fq * 8;
    const short8 ah0 = *(const short8*)&xh[arow + ko];
    const short8 ah1 = *(const short8*)&xh[arow + 32 + ko];
    const short8 ah2 = *(const short8*)&xh[arow + 64 + ko];
    const short8 am0 = *(const short8*)&xm[arow + ko];
    const short8 am1 = *(const short8*)&xm[arow + 32 + ko];
    const short8 am2 = *(const short8*)&xm[arow + 64 + ko];
    const short8 al0 = *(const short8*)&xl[arow + ko];
    const short8 al1 = *(const short8*)&xl[arow + 32 + ko];
    const short8 al2 = *(const short8*)&xl[arow + 64 + ko];

    // staging coordinates (mt-invariant): slots i=0,1 all threads, i=2 tid<128
    const int i0 = tid,        s0 = i0 / 384, re0 = i0 - s0 * 384;
    const int m_0 = re0 / 12,  c_0 = (re0 - m_0 * 12) * 8;
    const int i1 = tid + 512,  s1 = i1 / 384, re1 = i1 - s1 * 384;
    const int m_1 = re1 / 12,  c_1 = (re1 - m_1 * 12) * 8;
    const int i2 = tid + 1024, s2 = i2 / 384, re2 = i2 - s2 * 384;
    const int m_2 = re2 / 12,  c_2 = (re2 - m_2 * 12) * 8;
    const bool has2 = (tid < 128);
    const ushortT* bp0 = (s0 == 0) ? xh : ((s0 == 1) ? xm : xl);
    const ushortT* bp1 = (s1 == 0) ? xh : ((s1 == 1) ? xm : xl);
    const ushortT* bp2 = (s2 == 0) ? xh : ((s2 == 1) ? xm : xl);

    u64 kk0[9];
    #pragma unroll
    for (int j = 0; j < 9; j++) kk0[j] = 0xFFFFFFFFFFFFFFFFull;

    // prologue: stage shB[0] for mt=0
    {
        const int m0 = part * 448;
        *(float4*)&shB[0][s0][m_0][c_0] =
            *(const float4*)&bp0[((size_t)(b * NN + m0 + m_0)) * CC + c_0];
        *(float4*)&shB[0][s1][m_1][c_1] =
            *(const float4*)&bp1[((size_t)(b * NN + m0 + m_1)) * CC + c_1];
        if (has2)
            *(float4*)&shB[0][s2][m_2][c_2] =
                *(const float4*)&bp2[((size_t)(b * NN + m0 + m_2)) * CC + c_2];
    }

    const int mloc = Mt * 16 + fq * 4;    // this lane's first m within tile

    for (int mt = 0; mt < 14; mt++) {
        const int m0  = part * 448 + mt * 32;
        const int cur = mt & 1;

        // prefetch next tile into registers (issued before the barrier)
        float4 nxA, nxB, nxC;
        const bool hasn = (mt + 1) < 14;
        if (hasn) {
            const int m0n = m0 + 32;
            nxA = *(const float4*)&bp0[((size_t)(b * NN + m0n + m_0)) * CC + c_0];
            nxB = *(const float4*)&bp1[((size_t)(b * NN + m0n + m_1)) * CC + c_1];
            if (has2)
                nxC = *(const float4*)&bp2[((size_t)(b * NN + m0n + m_2)) * CC + c_2];
        }
        // epilogue inputs for this mt (4 contiguous f32 at this lane's m's)
        const float4 sqv = *(const float4*)&sqb[m0 + mloc];
        const float4 rpv = *(const float4*)&rp[(size_t)r * NN + m0 + mloc];

        __syncthreads();   // shB[cur] fully staged; prev reads of cur done

        // MFMA (operand-swapped): a = m-side frag, b = r-side frag -> D^T
        f32x4 acc = {0.f, 0.f, 0.f, 0.f};
        {
            const short8 bh = *(const short8*)&shB[cur][0][Mt * 16 + fr][ko];
            const short8 bm = *(const short8*)&shB[cur][1][Mt * 16 + fr][ko];
            const short8 bl = *(const short8*)&shB[cur][2][Mt * 16 + fr][ko];
            acc = __builtin_amdgcn_mfma_f32_16x16x32_bf16(bh, ah0, acc, 0, 0, 0);
            acc = __builtin_amdgcn_mfma_f32_16x16x32_bf16(bh, am0, acc, 0, 0, 0);
            acc = __builtin_amdgcn_mfma_f32_16x16x32_bf16(bm, ah0, acc, 0, 0, 0);
            acc = __builtin_amdgcn_mfma_f32_16x16x32_bf16(bm, am0, acc, 0, 0, 0);
            acc = __builtin_amdgcn_mfma_f32_16x16x32_bf16(bh, al0, acc, 0, 0, 0);
            acc = __builtin_amdgcn_mfma_f32_16x16x32_bf16(bl, ah0, acc, 0, 0, 0);
        }
        {
            const short8 bh = *(const short8*)&shB[cur][0][Mt * 16 + fr][32 + ko];
            const short8 bm = *(const short8*)&shB[cur][1][Mt * 16 + fr][32 + ko];
            const short8 bl = *(const short8*)&shB[cur][2][Mt * 16 + fr][32 + ko];
            acc = __builtin_amdgcn_mfma_f32_16x16x32_bf16(bh, ah1, acc, 0, 0, 0);
            acc = __builtin_amdgcn_mfma_f32_16x16x32_bf16(bh, am1, acc, 0, 0, 0);
            acc = __builtin_amdgcn_mfma_f32_16x16x32_bf16(bm, ah1, acc, 0, 0, 0);
            acc = __builtin_amdgcn_mfma_f32_16x16x32_bf16(bm, am1, acc, 0, 0, 0);
            acc = __builtin_amdgcn_mfma_f32_16x16x32_bf16(bh, al1, acc, 0, 0, 0);
            acc = __builtin_amdgcn_mfma_f32_16x16x32_bf16(bl, ah1, acc, 0, 0, 0);
        }
        {
            const short8 bh = *(const short8*)&shB[cur][0][Mt * 16 + fr][64 + ko];
            const short8 bm = *(const short8*)&shB[cur][1][Mt * 16 + fr][64 + ko];
            const short8 bl = *(const short8*)&shB[cur][2][Mt * 16 + fr][64 + ko];
            acc = __builtin_amdgcn_mfma_f32_16x16x32_bf16(bh, ah2, acc, 0, 0, 0);
            acc = __builtin_amdgcn_mfma_f32_16x16x32_bf16(bh, am2, acc, 0, 0, 0);
            acc = __builtin_amdgcn_mfma_f32_16x16x32_bf16(bm, ah2, acc, 0, 0, 0);
            acc = __builtin_amdgcn_mfma_f32_16x16x32_bf16(bm, am2, acc, 0, 0, 0);
            acc = __builtin_amdgcn_mfma_f32_16x16x32_bf16(bh, al2, acc, 0, 0, 0);
            acc = __builtin_amdgcn_mfma_f32_16x16x32_bf16(bl, ah2, acc, 0, 0, 0);
        }

        // write next buffer (safe: readers of cur^1 resume after next barrier)
        if (hasn) {
            const int nb = cur ^ 1;
            *(float4*)&shB[nb][s0][m_0][c_0] = nxA;
            *(float4*)&shB[nb][s1][m_1][c_1] = nxB;
            if (has2) *(float4*)&shB[nb][s2][m_2][c_2] = nxC;
        }

        // epilogue: lane holds row r, candidates m = m0 + mloc + q in acc[q]
        const int mb = m0 + mloc;
        ins9u(kk0, dkey(fmaf(-2.f, acc[0], sqv.x + rpv.x), mb + 0));
        ins9u(kk0, dkey(fmaf(-2.f, acc[1], sqv.y + rpv.y), mb + 1));
        ins9u(kk0, dkey(fmaf(-2.f, acc[2], sqv.z + rpv.z), mb + 2));
        ins9u(kk0, dkey(fmaf(-2.f, acc[3], sqv.w + rpv.w), mb + 3));
    }

    // tournament across the 4 fq-lanes of this row (xor 16, 32)
    const size_t base =
        (((size_t)(b * NN + r) * PARTS + part) * 2 + Mt) * KNB;
    #pragma unroll
    for (int k = 0; k < 9; k++) {
        u64 wv = kk0[0];
        #pragma unroll
        for (int off = 16; off < 64; off <<= 1) {
            unsigned int lo = __shfl_xor((unsigned int)wv, off);
            unsigned int hi = __shfl_xor((unsigned int)(wv >> 32), off);
            u64 o = ((u64)hi << 32) | lo;
            wv = (o < wv) ? o : wv;
        }
        if (kk0[0] == wv) {            // unique winner (keys contain m)
            #pragma unroll
            for (int j = 0; j < 8; j++) kk0[j] = kk0[j + 1];
            kk0[8] = 0xFFFFFFFFFFFFFFFFull;
        }
        if (fq == 0) pko[base + k] = wv;
    }
}

// ---------------------------------------------------------------------------
// Merge PARTS*2 sorted 9-lists (u64 keys) per (b,n) -> final nn_idx
// ---------------------------------------------------------------------------
__global__ __launch_bounds__(256) void knn_merge_kernel(
    const u64* __restrict__ pko, int* __restrict__ nn_idx)
{
    const int g = blockIdx.x * 256 + threadIdx.x;   // over B*N
    if (g >= BB * NN) return;
    u64 kk[9];
    #pragma unroll
    for (int j = 0; j < 9; j++) kk[j] = 0xFFFFFFFFFFFFFFFFull;
    const u64* v = pko + (size_t)g * PARTS * 2 * KNB;
    for (int p = 0; p < PARTS * 2; p++)
        #pragma unroll
        for (int j = 0; j < 9; j++)
            ins9u(kk, v[p * KNB + j]);
    #pragma unroll
    for (int j = 0; j < 9; j++)
        nn_idx[(size_t)g * KNB + j] = (int)(kk[j] & 0xFFFFFFFFu);
}

// ---------------------------------------------------------------------------
// Max-relative gather + channel interleave
// ---------------------------------------------------------------------------
__global__ __launch_bounds__(256) void gather_kernel(
    const float* __restrict__ xf, const int* __restrict__ nn_idx,
    float* __restrict__ y)
{
    const size_t g = (size_t)blockIdx.x * 256 + threadIdx.x;   // over B*C*N
    const int n  = (int)(g % NN);
    const int bc = (int)(g / NN);
    const int c  = bc % CC;
    const int b  = bc / CC;
    const float* row = xf + (size_t)(b * CC + c) * NN;
    const float xi = row[n];
    const int* id = nn_idx + ((size_t)b * NN + n) * KNB;
    float mx = -FLT_MAX_;
    #pragma unroll
    for (int k = 0; k < KNB; k++) mx = fmaxf(mx, row[id[k]] - xi);
    float* o = y + ((size_t)b * 2 * CC + 2 * c) * NN + n;
    o[0]  = xi;
    o[NN] = mx;
}

// ---------------------------------------------------------------------------
// Host-side orchestration
// ---------------------------------------------------------------------------
static void conv1(const float* in, const float* w, const float* b, float* out,
                  int K, int O, hipStream_t s)
{
    dim3 grid(NN / 64, (O + 63) / 64, BB);
    conv1_kernel<<<grid, 256, 0, s>>>(in, w, b, out, K, O);
}
static void inorm(const float* in, float* out, const float* res, int ch, int act,
                  hipStream_t s)
{
    inorm_kernel<<<BB * ch, 256, 0, s>>>(in, out, res, act);
}

struct GrapherP {
    const float *fc1w, *fc1b, *mrw, *mrb, *fc2w, *fc2b;
};

static void run_grapher(const float* in, const float* rp, const GrapherP& p,
                        float* outCur, float* bufA, float* bufB,
                        ushortT* xh, ushortT* xm, ushortT* xl,
                        float* sqc, int* idx, hipStream_t s)
{
    conv1(in, p.fc1w, p.fc1b, bufA, CC, CC, s);
    inorm(bufA, bufB, nullptr, CC, 0, s);                         // xf
    colnorm_kernel<<<(BB * NN) / 256, 256, 0, s>>>(bufB, xh, xm, xl, sqc);
    // partial-key scratch lives in bufA (free until gather writes it):
    // B*N*PARTS*2*9 u64 = 25.3 MB < bufA (38.5 MB)
    u64* pko = (u64*)bufA;
    knn_mfma_kernel<<<dim3(NN / 64, PARTS, BB), 512, 0, s>>>(
        xh, xm, xl, sqc, rp, pko);
    knn_merge_kernel<<<(BB * NN + 255) / 256, 256, 0, s>>>(pko, idx);
    gather_kernel<<<(BB * CC * NN) / 256, 256, 0, s>>>(bufB, idx, bufA);  // 2C
    conv1(bufA, p.mrw, p.mrb, bufB, 2 * CC, 2 * CC, s);
    inorm(bufB, bufA, nullptr, 2 * CC, 1, s);                     // gelu
    conv1(bufA, p.fc2w, p.fc2b, bufB, 2 * CC, CC, s);
    inorm(bufB, outCur, in, CC, 0, s);                            // + shortcut
}

static void run_ffn(const float* in, const float* w1, const float* b1,
                    const float* w2, const float* b2,
                    float* outCur, float* bufA, float* bufB, hipStream_t s)
{
    conv1(in, w1, b1, bufA, CC, 4 * CC, s);
    inorm(bufA, bufB, nullptr, 4 * CC, 1, s);                     // gelu
    conv1(bufB, w2, b2, bufA, 2 * CC * 2, CC, s);
    inorm(bufA, outCur, in, CC, 0, s);                            // + shortcut
}

extern "C" void kernel_launch(void* const* d_in, const int* in_sizes, int n_in,
                              void* d_out, int out_size, void* d_ws, size_t ws_size,
                              hipStream_t stream)
{
    const float* x  = (const float*)d_in[0];
    const float* rp = (const float*)d_in[1];
    GrapherP g1 = {(const float*)d_in[2],  (const float*)d_in[3],
                   (const float*)d_in[4],  (const float*)d_in[5],
                   (const float*)d_in[6],  (const float*)d_in[7]};
    GrapherP g2 = {(const float*)d_in[8],  (const float*)d_in[9],
                   (const float*)d_in[10], (const float*)d_in[11],
                   (const float*)d_in[12], (const float*)d_in[13]};
    const float* f1w1 = (const float*)d_in[14]; const float* f1b1 = (const float*)d_in[15];
    const float* f1w2 = (const float*)d_in[16]; const float* f1b2 = (const float*)d_in[17];
    const float* f2w1 = (const float*)d_in[18]; const float* f2b1 = (const float*)d_in[19];
    const float* f2w2 = (const float*)d_in[20]; const float* f2b2 = (const float*)d_in[21];
    float* out = (float*)d_out;

    const size_t P  = (size_t)BB * CC * NN;     // 2,408,448 elements
    const size_t P4 = 4 * P;
    float* ws   = (float*)d_ws;
    float* bufA = ws;                 // P4 floats
    float* bufB = bufA + P4;          // P4
    float* cur0 = bufB + P4;          // P
    float* cur1 = cur0 + P;           // P
    float* sqc  = cur1 + P;           // B*N
    int*   idx  = (int*)(sqc + (size_t)BB * NN);        // B*N*9 ints
    ushortT* xh = (ushortT*)(idx + (size_t)BB * NN * KNB);  // P ushorts
    ushortT* xm = xh + P;                                    // P ushorts
    ushortT* xl = xm + P;                                    // P ushorts

    run_grapher(x, rp, g1, cur0, bufA, bufB, xh, xm, xl, sqc, idx, stream);
    run_ffn(cur0, f1w1, f1b1, f1w2, f1b2, cur1, bufA, bufB, stream);
    inorm(cur1, cur0, nullptr, CC, 2, stream);
    run_grapher(cur0, rp, g2, cur1, bufA, bufB, xh, xm, xl, sqc, idx, stream);
    run_ffn(cur1, f2w1, f2b1, f2w2, f2b2, cur0, bufA, bufB, stream);
    inorm(cur0, out, x, CC, 0, stream);
    (void)in_sizes; (void)n_in; (void)out_size; (void)ws_size;
}